// Round 9
// baseline (1413.189 us; speedup 1.0000x reference)
//
#include <hip/hip_runtime.h>
#include <math.h>

#define BB 2
#define NN 40960
#define KK 16

typedef float v2f __attribute__((ext_vector_type(2)));
__device__ __forceinline__ v2f mk2(float a, float b){ v2f r; r.x=a; r.y=b; return r; }
__device__ __forceinline__ v2f fma2(v2f a, v2f b, v2f c){
  return __builtin_elementwise_fma(a, b, c);
}

// intra-wave LDS producer->consumer fence (no cross-wave sharing, so no s_barrier)
__device__ __forceinline__ void wave_sync(){
  asm volatile("s_waitcnt lgkmcnt(0)" ::: "memory");
  __builtin_amdgcn_sched_barrier(0);
}

// ---- BN-folded weights, computed once (30.6 KB) ----
__device__ alignas(16) float g_pw1[32*10];
__device__ alignas(16) float g_pb1[32];
__device__ alignas(16) float g_pw2[32*32];
__device__ alignas(16) float g_pb2[32];
__device__ alignas(16) float g_pcw[32*64];   // ap1 mlp folded
__device__ alignas(16) float g_pcb[32];
__device__ alignas(16) float g_pdw[64*64];   // ap2 mlp folded
__device__ alignas(16) float g_pdb[64];

// Fused: feature transpose (blocks 0..319) + BN-fold prep (last block)
__global__ __launch_bounds__(256) void k_pre(
  const float* __restrict__ feat, float* __restrict__ feat_t,
  const float* __restrict__ w1, const float* __restrict__ b1,
  const float* __restrict__ g1, const float* __restrict__ be1, const float* __restrict__ m1, const float* __restrict__ v1,
  const float* __restrict__ w2, const float* __restrict__ b2,
  const float* __restrict__ g2, const float* __restrict__ be2, const float* __restrict__ m2, const float* __restrict__ v2,
  const float* __restrict__ cw, const float* __restrict__ cb,
  const float* __restrict__ cg, const float* __restrict__ cbe, const float* __restrict__ cm, const float* __restrict__ cv,
  const float* __restrict__ dw, const float* __restrict__ db,
  const float* __restrict__ dg, const float* __restrict__ dbe, const float* __restrict__ dm, const float* __restrict__ dv)
{
  int tid = threadIdx.x;
  int bid = blockIdx.x;
  if (bid < BB*NN/256){
    int b = bid / (NN/256);
    int n = (bid % (NN/256))*256 + tid;
    float v[32];
    #pragma unroll
    for (int h=0; h<32; ++h) v[h] = feat[((size_t)(b*32+h))*NN + n];
    float* o = feat_t + ((size_t)b*NN + n)*32;
    #pragma unroll
    for (int h=0; h<32; h+=4){ *(float4*)(o+h) = make_float4(v[h],v[h+1],v[h+2],v[h+3]); }
    return;
  }
  for (int i=tid; i<320; i+=256){ int h=i/10;
    g_pw1[i] = w1[i] * (g1[h]*rsqrtf(v1[h]+1e-5f)); }
  if (tid<32){ float s=g1[tid]*rsqrtf(v1[tid]+1e-5f);
    g_pb1[tid] = (b1[tid]-m1[tid])*s + be1[tid]; }
  for (int i=tid; i<1024; i+=256){ int h=i>>5;
    g_pw2[i] = w2[i] * (g2[h]*rsqrtf(v2[h]+1e-5f)); }
  if (tid<32){ float s=g2[tid]*rsqrtf(v2[tid]+1e-5f);
    g_pb2[tid] = (b2[tid]-m2[tid])*s + be2[tid]; }
  for (int i=tid; i<2048; i+=256){ int h=i>>6;
    g_pcw[i] = cw[i] * (cg[h]*rsqrtf(cv[h]+1e-5f)); }
  if (tid<32){ float s=cg[tid]*rsqrtf(cv[tid]+1e-5f);
    g_pcb[tid] = (cb[tid]-cm[tid])*s + cbe[tid]; }
  for (int i=tid; i<4096; i+=256){ int h=i>>6;
    g_pdw[i] = dw[i] * (dg[h]*rsqrtf(dv[h]+1e-5f)); }
  if (tid<64){ float s=dg[tid]*rsqrtf(dv[tid]+1e-5f);
    g_pdb[tid] = (db[tid]-dm[tid])*s + dbe[tid]; }
}

// ========== Wave-per-point kernels: lane = output channel, weights VGPR-resident ==========
// LDS f_cat row pitch 68 floats (272B) to spread row-start banks.

__global__ __launch_bounds__(256,3) void k_stage1(
  const float* __restrict__ xyz, const float* __restrict__ feat_t, const int* __restrict__ nidx,
  const float* __restrict__ fcw, const float* __restrict__ fcb,
  float* __restrict__ fagg)
{
  __shared__ float s_fcat[4][16*68];
  __shared__ float s_agg[4][64];
  int tid = threadIdx.x, lane = tid&63, wvv = tid>>6;
  int j = lane&15, cb = lane>>4;
  int h_ap = lane&31, half = lane>>5;

  // per-lane weight rows -> registers (loaded ONCE)
  float fcw_r[64];
  {
    const float4* src = (const float4*)(fcw + lane*64);
    #pragma unroll
    for (int c4=0;c4<16;++c4){ float4 w=src[c4];
      fcw_r[4*c4]=w.x; fcw_r[4*c4+1]=w.y; fcw_r[4*c4+2]=w.z; fcw_r[4*c4+3]=w.w; }
  }
  float fcb_r = fcb[lane];
  float pcw_r[32];
  {
    const float4* src = (const float4*)(g_pcw + h_ap*64 + half*32);
    #pragma unroll
    for (int c4=0;c4<8;++c4){ float4 w=src[c4];
      pcw_r[4*c4]=w.x; pcw_r[4*c4+1]=w.y; pcw_r[4*c4+2]=w.z; pcw_r[4*c4+3]=w.w; }
  }
  float pcb_r = g_pcb[h_ap];

  float* fcp = &s_fcat[wvv][0];
  float* agp = &s_agg[wvv][0];
  int pn0 = (blockIdx.x*4 + wvv)*16;
  int b = (pn0 >= NN) ? 1 : 0;
  int base = b*NN;

  for (int t=0; t<16; ++t){
    int pn = pn0 + t;
    int idx = nidx[(size_t)pn*KK + j];
    // early gather (f_nb) — latency hides under enc+mlp1
    const float4* fbp = (const float4*)(feat_t + ((size_t)(base+idx))*32 + cb*8);
    float4 g0 = fbp[0], g1 = fbp[1];

    const float* tp = xyz + (size_t)pn*3;
    const float* qp = xyz + (size_t)(base+idx)*3;
    float t0=tp[0],t1=tp[1],t2=tp[2];
    float q0=qp[0],q1=qp[1],q2=qp[2];
    float r0=t0-q0,r1=t1-q1,r2=t2-q2;
    v2f e2[5] = { {sqrtf(r0*r0+r1*r1+r2*r2),r0},{r1,r2},{t0,t1},{t2,q0},{q1,q2} };

    // mlp1 for this lane's j (uniform weights -> scalar loads)
    float fx[32];
    #pragma unroll
    for (int h=0; h<32; ++h){
      const v2f* wr = (const v2f*)(g_pw1 + h*10);
      v2f a = mk2(g_pb1[h], 0.f);
      #pragma unroll
      for (int c=0;c<5;++c) a = fma2(wr[c], e2[c], a);
      fx[h] = fmaxf(a.x+a.y, 0.f);
    }
    // stage f_cat: cols 0..31 = f_nb, cols 32..63 = f_xyz
    *(float4*)(fcp + j*68 + cb*8)     = g0;
    *(float4*)(fcp + j*68 + cb*8 + 4) = g1;
    if (lane < 16){
      #pragma unroll
      for (int c4=0;c4<8;++c4)
        *(float4*)(fcp + j*68 + 32 + c4*4) =
          make_float4(fx[4*c4],fx[4*c4+1],fx[4*c4+2],fx[4*c4+3]);
    }
    wave_sync();

    // fc1: lane o = lane; 16 independent acc chains, weights in VGPR
    float acc[16];
    #pragma unroll
    for (int j2=0;j2<16;++j2) acc[j2] = fcb_r;
    #pragma unroll
    for (int j2=0;j2<16;++j2){
      const float4* fr = (const float4*)(fcp + j2*68);
      #pragma unroll
      for (int c4=0;c4<16;++c4){
        float4 f = fr[c4];
        acc[j2]=fmaf(fcw_r[4*c4+0],f.x,acc[j2]);
        acc[j2]=fmaf(fcw_r[4*c4+1],f.y,acc[j2]);
        acc[j2]=fmaf(fcw_r[4*c4+2],f.z,acc[j2]);
        acc[j2]=fmaf(fcw_r[4*c4+3],f.w,acc[j2]);
      }
    }
    // softmax over k: fully lane-local (relu'd logits -> no max-sub needed)
    float sp=0.f, sfp=0.f;
    #pragma unroll
    for (int j2=0;j2<16;++j2){ acc[j2] = __expf(fmaxf(acc[j2],0.f)); sp += acc[j2]; }
    #pragma unroll
    for (int j2=0;j2<16;++j2){ sfp = fmaf(fcp[j2*68 + lane], acc[j2], sfp); }
    float aggv = __fdividef(sfp, sp);
    agp[lane] = aggv;
    wave_sync();

    // ap1: h = lane&31, each half sums 32 cols, combine via shfl_xor(32)
    float part = 0.f;
    const float4* ar = (const float4*)(agp + half*32);
    #pragma unroll
    for (int c4=0;c4<8;++c4){
      float4 a = ar[c4];
      part=fmaf(pcw_r[4*c4+0],a.x,part);
      part=fmaf(pcw_r[4*c4+1],a.y,part);
      part=fmaf(pcw_r[4*c4+2],a.z,part);
      part=fmaf(pcw_r[4*c4+3],a.w,part);
    }
    part += __shfl_xor(part, 32);
    float val = fmaxf(part + pcb_r, 0.f);
    if (lane < 32) fagg[(size_t)pn*32 + lane] = val;   // coalesced 128B row
    wave_sync();
  }
}

__global__ __launch_bounds__(256,3) void k_stage2(
  const float* __restrict__ xyz, const float* __restrict__ fagg, const int* __restrict__ nidx,
  const float* __restrict__ fcw, const float* __restrict__ fcb,
  float* __restrict__ outp)
{
  __shared__ float s_fcat[4][16*68];
  __shared__ float s_agg[4][64];
  __shared__ float s_out[4][64*17];
  __shared__ float s_w2[32*36];
  int tid = threadIdx.x, lane = tid&63, wvv = tid>>6;
  int j = lane&15, cb = lane>>4;

  for (int i=tid; i<32*36; i+=256){ int h=i/36, c=i-h*36;
    s_w2[i] = (c<32) ? g_pw2[h*32+c] : 0.f; }
  __syncthreads();

  float fcw_r[64];   // fc2 row for this lane's channel
  {
    const float4* src = (const float4*)(fcw + lane*64);
    #pragma unroll
    for (int c4=0;c4<16;++c4){ float4 w=src[c4];
      fcw_r[4*c4]=w.x; fcw_r[4*c4+1]=w.y; fcw_r[4*c4+2]=w.z; fcw_r[4*c4+3]=w.w; }
  }
  float fcb_r = fcb[lane];
  float pdb_r = g_pdb[lane];
  float pb2_r[8];
  #pragma unroll
  for (int r=0;r<8;++r) pb2_r[r] = g_pb2[cb*8 + r];

  float* fcp = &s_fcat[wvv][0];
  float* agp = &s_agg[wvv][0];
  float* sow = &s_out[wvv][0];
  int pn0 = (blockIdx.x*4 + wvv)*16;
  int b = (pn0 >= NN) ? 1 : 0;
  int base = b*NN;

  for (int t=0; t<16; ++t){
    int pn = pn0 + t;
    int idx = nidx[(size_t)pn*KK + j];
    const float4* fbp = (const float4*)(fagg + ((size_t)(base+idx))*32 + cb*8);
    float4 g0 = fbp[0], g1 = fbp[1];

    const float* tp = xyz + (size_t)pn*3;
    const float* qp = xyz + (size_t)(base+idx)*3;
    float t0=tp[0],t1=tp[1],t2=tp[2];
    float q0=qp[0],q1=qp[1],q2=qp[2];
    float r0=t0-q0,r1=t1-q1,r2=t2-q2;
    v2f e2[5] = { {sqrtf(r0*r0+r1*r1+r2*r2),r0},{r1,r2},{t0,t1},{t2,q0},{q1,q2} };

    // mlp1 for this lane's j (4 lanes sharing j compute identical fx -> no LDS round-trip)
    float fx[32];
    #pragma unroll
    for (int h=0; h<32; ++h){
      const v2f* wr = (const v2f*)(g_pw1 + h*10);
      v2f a = mk2(g_pb1[h], 0.f);
      #pragma unroll
      for (int c=0;c<5;++c) a = fma2(wr[c], e2[c], a);
      fx[h] = fmaxf(a.x+a.y, 0.f);
    }
    // mlp2: this lane computes channels h = cb*8 .. cb*8+7 for its j, from its own fx
    float m8[8];
    #pragma unroll
    for (int r=0;r<8;++r){
      const float4* wr = (const float4*)(s_w2 + (cb*8+r)*36);
      float a = pb2_r[r];
      #pragma unroll
      for (int c4=0;c4<8;++c4){
        float4 w = wr[c4];
        a=fmaf(w.x,fx[4*c4+0],a); a=fmaf(w.y,fx[4*c4+1],a);
        a=fmaf(w.z,fx[4*c4+2],a); a=fmaf(w.w,fx[4*c4+3],a);
      }
      m8[r] = fmaxf(a, 0.f);
    }
    // stage f_cat: cols 0..31 = f_nb(gathered fagg), 32..63 = mlp2 out
    *(float4*)(fcp + j*68 + cb*8)       = g0;
    *(float4*)(fcp + j*68 + cb*8 + 4)   = g1;
    *(float4*)(fcp + j*68 + 32 + cb*8)     = make_float4(m8[0],m8[1],m8[2],m8[3]);
    *(float4*)(fcp + j*68 + 32 + cb*8 + 4) = make_float4(m8[4],m8[5],m8[6],m8[7]);
    wave_sync();

    // fc2
    float acc[16];
    #pragma unroll
    for (int j2=0;j2<16;++j2) acc[j2] = fcb_r;
    #pragma unroll
    for (int j2=0;j2<16;++j2){
      const float4* fr = (const float4*)(fcp + j2*68);
      #pragma unroll
      for (int c4=0;c4<16;++c4){
        float4 f = fr[c4];
        acc[j2]=fmaf(fcw_r[4*c4+0],f.x,acc[j2]);
        acc[j2]=fmaf(fcw_r[4*c4+1],f.y,acc[j2]);
        acc[j2]=fmaf(fcw_r[4*c4+2],f.z,acc[j2]);
        acc[j2]=fmaf(fcw_r[4*c4+3],f.w,acc[j2]);
      }
    }
    float sp=0.f, sfp=0.f;
    #pragma unroll
    for (int j2=0;j2<16;++j2){ acc[j2] = __expf(fmaxf(acc[j2],0.f)); sp += acc[j2]; }
    #pragma unroll
    for (int j2=0;j2<16;++j2){ sfp = fmaf(fcp[j2*68 + lane], acc[j2], sfp); }
    float aggv = __fdividef(sfp, sp);
    agp[lane] = aggv;
    wave_sync();

    // ap2: lane = output channel (64); weights from global (L1-resident 16KB)
    float part = 0.f;
    const float4* wp = (const float4*)(g_pdw + lane*64);
    const float4* ar = (const float4*)agp;
    #pragma unroll
    for (int c4=0;c4<16;++c4){
      float4 w = wp[c4];
      float4 a = ar[c4];
      part=fmaf(w.x,a.x,part); part=fmaf(w.y,a.y,part);
      part=fmaf(w.z,a.z,part); part=fmaf(w.w,a.w,part);
    }
    sow[lane*17 + t] = fmaxf(part + pdb_r, 0.f);
    wave_sync();
  }
  // batched output: lane writes its channel's 16 consecutive n (64B, fully-used sectors)
  {
    int n0l = pn0 - base;
    float* orow = outp + ((size_t)(b*64 + lane))*NN + n0l;
    #pragma unroll
    for (int q=0;q<4;++q){
      float4 v = make_float4(sow[lane*17+4*q], sow[lane*17+4*q+1],
                             sow[lane*17+4*q+2], sow[lane*17+4*q+3]);
      *(float4*)(orow + 4*q) = v;
    }
  }
}

extern "C" void kernel_launch(void* const* d_in, const int* in_sizes, int n_in,
                              void* d_out, int out_size, void* d_ws, size_t ws_size,
                              hipStream_t stream){
  const float* xyz     = (const float*)d_in[0];
  const float* feature = (const float*)d_in[1];
  const int*   nidx    = (const int*)d_in[30];
  float* feat_t = (float*)d_ws;                       // (B,N,32)
  float* fagg   = feat_t + (size_t)BB*NN*32;          // (B,N,32)

  k_pre<<<BB*NN/256 + 1, 256, 0, stream>>>(feature, feat_t,
    (const float*)d_in[2],(const float*)d_in[3],(const float*)d_in[4],(const float*)d_in[5],
    (const float*)d_in[6],(const float*)d_in[7],
    (const float*)d_in[16],(const float*)d_in[17],(const float*)d_in[18],(const float*)d_in[19],
    (const float*)d_in[20],(const float*)d_in[21],
    (const float*)d_in[10],(const float*)d_in[11],(const float*)d_in[12],(const float*)d_in[13],
    (const float*)d_in[14],(const float*)d_in[15],
    (const float*)d_in[24],(const float*)d_in[25],(const float*)d_in[26],(const float*)d_in[27],
    (const float*)d_in[28],(const float*)d_in[29]);
  // 81920 points / (4 waves * 16 pts) = 1280 blocks
  k_stage1<<<BB*NN/64, 256, 0, stream>>>(xyz, feat_t, nidx,
    (const float*)d_in[8],(const float*)d_in[9], fagg);
  k_stage2<<<BB*NN/64, 256, 0, stream>>>(xyz, fagg, nidx,
    (const float*)d_in[22],(const float*)d_in[23], (float*)d_out);
}

// Round 10
// 753.960 us; speedup vs baseline: 1.8744x; 1.8744x over previous
//
#include <hip/hip_runtime.h>
#include <math.h>

#define BB 2
#define NN 40960
#define KK 16

typedef __attribute__((ext_vector_type(8))) short bf16x8;
typedef __attribute__((ext_vector_type(4))) float f32x4;
typedef unsigned int u32;
typedef unsigned short u16;
typedef float v2f __attribute__((ext_vector_type(2)));

#define MFMA16 __builtin_amdgcn_mfma_f32_16x16x32_bf16

__device__ __forceinline__ v2f fma2(v2f a, v2f b, v2f c){ return __builtin_elementwise_fma(a,b,c); }
__device__ __forceinline__ v2f mk2(float a, float b){ v2f r; r.x=a; r.y=b; return r; }
__device__ __forceinline__ u16 f2bf(float x){
  u32 u = __float_as_uint(x);
  return (u16)((u + 0x7FFFu + ((u>>16)&1u)) >> 16);   // RNE truncate to bf16
}
__device__ __forceinline__ float bf2f(u16 h){ return __uint_as_float(((u32)h)<<16); }
__device__ __forceinline__ u32 pk2(u16 a, u16 b){ return (u32)a | ((u32)b<<16); }

template<int CTRL>
__device__ __forceinline__ float dppf(float x){
  return __int_as_float(__builtin_amdgcn_update_dpp(0, __float_as_int(x), CTRL, 0xF, 0xF, true));
}
__device__ __forceinline__ float red16_sum(float v){
  v += dppf<0xB1>(v); v += dppf<0x4E>(v); v += dppf<0x141>(v); v += dppf<0x140>(v);
  return v;
}
// intra-wave LDS producer->consumer fence (no cross-wave LDS sharing)
__device__ __forceinline__ void wave_sync(){
  asm volatile("s_waitcnt lgkmcnt(0)" ::: "memory");
  __builtin_amdgcn_sched_barrier(0);
}

// ---- precomputed MFMA A-fragments (bf16 hi/lo split; A: m=lane&15, k=8*(lane>>4)+j) ----
__device__ alignas(16) u16 g_fc1h[4][2][64][8], g_fc1l[4][2][64][8];
__device__ alignas(16) u16 g_fc2h[4][2][64][8], g_fc2l[4][2][64][8];
__device__ alignas(16) u16 g_ap1h[2][2][64][8], g_ap1l[2][2][64][8];
__device__ alignas(16) u16 g_ap2h[4][2][64][8], g_ap2l[4][2][64][8];
__device__ alignas(16) u16 g_m2h[2][64][8],     g_m2l[2][64][8];
__device__ alignas(16) float g_pw1[32*10];
__device__ float g_pb1[32], g_pb2[32], g_pcb[32], g_pdb[64];

// Fused: feature transpose (blocks 0..319) + frag/fold prep (last block)
__global__ __launch_bounds__(256) void k_pre(
  const float* __restrict__ feat, float* __restrict__ feat_t,
  const float* __restrict__ w1, const float* __restrict__ b1,
  const float* __restrict__ g1, const float* __restrict__ be1, const float* __restrict__ m1, const float* __restrict__ v1,
  const float* __restrict__ fc1w,
  const float* __restrict__ cw, const float* __restrict__ cb,
  const float* __restrict__ cg, const float* __restrict__ cbe, const float* __restrict__ cm, const float* __restrict__ cv,
  const float* __restrict__ w2, const float* __restrict__ b2,
  const float* __restrict__ g2, const float* __restrict__ be2, const float* __restrict__ m2, const float* __restrict__ v2,
  const float* __restrict__ fc2w,
  const float* __restrict__ dw, const float* __restrict__ db,
  const float* __restrict__ dg, const float* __restrict__ dbe, const float* __restrict__ dm, const float* __restrict__ dv)
{
  int tid = threadIdx.x, bid = blockIdx.x;
  if (bid < BB*NN/256){
    int b = bid / (NN/256);
    int n = (bid % (NN/256))*256 + tid;
    float v[32];
    #pragma unroll
    for (int h=0; h<32; ++h) v[h] = feat[((size_t)(b*32+h))*NN + n];
    float* o = feat_t + ((size_t)b*NN + n)*32;
    #pragma unroll
    for (int h=0; h<32; h+=4) *(float4*)(o+h) = make_float4(v[h],v[h+1],v[h+2],v[h+3]);
    return;
  }
  for (int i=tid; i<320; i+=256){ int h=i/10; g_pw1[i] = w1[i]*(g1[h]*rsqrtf(v1[h]+1e-5f)); }
  if (tid<32){ float s=g1[tid]*rsqrtf(v1[tid]+1e-5f); g_pb1[tid]=(b1[tid]-m1[tid])*s+be1[tid]; }
  if (tid<32){ float s=g2[tid]*rsqrtf(v2[tid]+1e-5f); g_pb2[tid]=(b2[tid]-m2[tid])*s+be2[tid]; }
  if (tid<32){ float s=cg[tid]*rsqrtf(cv[tid]+1e-5f); g_pcb[tid]=(cb[tid]-cm[tid])*s+cbe[tid]; }
  if (tid<64){ float s=dg[tid]*rsqrtf(dv[tid]+1e-5f); g_pdb[tid]=(db[tid]-dm[tid])*s+dbe[tid]; }
  // fc1 / fc2 / ap2 fragments (4 o-tiles x 2 k-tiles)
  for (int i=tid; i<4096; i+=256){
    int ot=i>>10, rr=i&1023, kt=rr>>9, r2=rr&511, ln=r2>>3, jj=r2&7;
    int o = ot*16 + (ln&15), c = kt*32 + 8*(ln>>4) + jj;
    float a = fc1w[o*64+c]; u16 ha=f2bf(a);
    g_fc1h[ot][kt][ln][jj]=ha; g_fc1l[ot][kt][ln][jj]=f2bf(a-bf2f(ha));
    float bq = fc2w[o*64+c]; u16 hb=f2bf(bq);
    g_fc2h[ot][kt][ln][jj]=hb; g_fc2l[ot][kt][ln][jj]=f2bf(bq-bf2f(hb));
    float sd = dg[o]*rsqrtf(dv[o]+1e-5f);
    float cq = dw[o*64+c]*sd; u16 hc=f2bf(cq);
    g_ap2h[ot][kt][ln][jj]=hc; g_ap2l[ot][kt][ln][jj]=f2bf(cq-bf2f(hc));
  }
  // ap1 fragments (2 o-tiles x 2 k-tiles)
  for (int i=tid; i<2048; i+=256){
    int ot=i>>10, rr=i&1023, kt=rr>>9, r2=rr&511, ln=r2>>3, jj=r2&7;
    int h = ot*16 + (ln&15), c = kt*32 + 8*(ln>>4) + jj;
    float sc = cg[h]*rsqrtf(cv[h]+1e-5f);
    float a = cw[h*64+c]*sc; u16 ha=f2bf(a);
    g_ap1h[ot][kt][ln][jj]=ha; g_ap1l[ot][kt][ln][jj]=f2bf(a-bf2f(ha));
  }
  // mlp2 fragments (2 o-tiles, K=32)
  for (int i=tid; i<1024; i+=256){
    int ot=i>>9, rr=i&511, ln=rr>>3, jj=rr&7;
    int h = ot*16 + (ln&15), c = 8*(ln>>4) + jj;
    float s2 = g2[h]*rsqrtf(v2[h]+1e-5f);
    float a = w2[h*32+c]*s2; u16 ha=f2bf(a);
    g_m2h[ot][ln][jj]=ha; g_m2l[ot][ln][jj]=f2bf(a-bf2f(ha));
  }
}

// Wave = 16 consecutive points; lane = (neighbor kq = lane&15, group g = lane>>4).
// F LDS: [nbr][72] bf16 hi/lo; agg LDS: [point t][72] hi/lo.
__global__ __launch_bounds__(256,3) void k_stage1(
  const float* __restrict__ xyz, const float* __restrict__ feat_t, const int* __restrict__ nidx,
  const float* __restrict__ fcb, float* __restrict__ fagg)
{
  __shared__ u16 sFh[4][16*72], sFl[4][16*72];
  __shared__ u16 sAh[4][16*72], sAl[4][16*72];
  int tid=threadIdx.x, lane=tid&63, wv=tid>>6;
  int kq=lane&15, g=lane>>4;
  u16 *Fh=&sFh[wv][0], *Fl=&sFl[wv][0], *Agh=&sAh[wv][0], *Agl=&sAl[wv][0];
  int pn0 = (blockIdx.x*4 + wv)*16;
  int b = (pn0 >= NN) ? 1 : 0;
  int base = b*NN;

  float fcbv[16], pcbv[8];
  #pragma unroll
  for (int ot=0;ot<4;++ot)
    #pragma unroll
    for (int r=0;r<4;++r) fcbv[ot*4+r] = fcb[ot*16 + g*4 + r];
  #pragma unroll
  for (int ot=0;ot<2;++ot)
    #pragma unroll
    for (int r=0;r<4;++r) pcbv[ot*4+r] = g_pcb[ot*16 + g*4 + r];

  #pragma unroll 1
  for (int t=0;t<16;++t){
    int pn = pn0 + t;
    int idx = nidx[(size_t)pn*KK + kq];
    const float4* fbp = (const float4*)(feat_t + ((size_t)(base+idx))*32 + g*8);
    float4 nb0 = fbp[0], nb1 = fbp[1];

    const float* tp = xyz + (size_t)pn*3;
    const float* qp = xyz + (size_t)(base+idx)*3;
    float t0=tp[0],t1=tp[1],t2=tp[2], q0=qp[0],q1=qp[1],q2=qp[2];
    float r0=t0-q0,r1=t1-q1,r2=t2-q2;
    v2f e2[5] = { mk2(sqrtf(r0*r0+r1*r1+r2*r2),r0), mk2(r1,r2), mk2(t0,t1), mk2(t2,q0), mk2(q1,q2) };

    float fx[32];
    #pragma unroll
    for (int h=0;h<32;++h){
      const v2f* wr = (const v2f*)(g_pw1 + h*10);
      v2f a = mk2(g_pb1[h], 0.f);
      #pragma unroll
      for (int c=0;c<5;++c) a = fma2(wr[c], e2[c], a);
      fx[h] = fmaxf(a.x+a.y, 0.f);
    }
    { // stage f_nb (cols g*8..g*8+7)
      float vv[8] = {nb0.x,nb0.y,nb0.z,nb0.w, nb1.x,nb1.y,nb1.z,nb1.w};
      u16 hs[8], ls[8];
      #pragma unroll
      for (int j=0;j<8;++j){ hs[j]=f2bf(vv[j]); ls[j]=f2bf(vv[j]-bf2f(hs[j])); }
      uint4 ph, pl;
      ph.x=pk2(hs[0],hs[1]); ph.y=pk2(hs[2],hs[3]); ph.z=pk2(hs[4],hs[5]); ph.w=pk2(hs[6],hs[7]);
      pl.x=pk2(ls[0],ls[1]); pl.y=pk2(ls[2],ls[3]); pl.z=pk2(ls[4],ls[5]); pl.w=pk2(ls[6],ls[7]);
      *(uint4*)&Fh[kq*72 + g*8] = ph;
      *(uint4*)&Fl[kq*72 + g*8] = pl;
    }
    if (lane < 16){ // stage f_xyz (cols 32..63), one writer per neighbor row
      #pragma unroll
      for (int c4=0;c4<4;++c4){
        u16 hs[8], ls[8];
        #pragma unroll
        for (int j=0;j<8;++j){ float v=fx[c4*8+j]; hs[j]=f2bf(v); ls[j]=f2bf(v-bf2f(hs[j])); }
        uint4 ph, pl;
        ph.x=pk2(hs[0],hs[1]); ph.y=pk2(hs[2],hs[3]); ph.z=pk2(hs[4],hs[5]); ph.w=pk2(hs[6],hs[7]);
        pl.x=pk2(ls[0],ls[1]); pl.y=pk2(ls[2],ls[3]); pl.z=pk2(ls[4],ls[5]); pl.w=pk2(ls[6],ls[7]);
        *(uint4*)&Fh[kq*72 + 32 + c4*8] = ph;
        *(uint4*)&Fl[kq*72 + 32 + c4*8] = pl;
      }
    }
    wave_sync();
    // fc1 via MFMA split: Whi*Fhi + Whi*Flo + Wlo*Fhi
    bf16x8 bh0 = *(const bf16x8*)&Fh[kq*72 + 8*g];
    bf16x8 bh1 = *(const bf16x8*)&Fh[kq*72 + 32 + 8*g];
    bf16x8 bl0 = *(const bf16x8*)&Fl[kq*72 + 8*g];
    bf16x8 bl1 = *(const bf16x8*)&Fl[kq*72 + 32 + 8*g];
    #pragma unroll
    for (int ot=0;ot<4;++ot){
      bf16x8 ah0 = *(const bf16x8*)&g_fc1h[ot][0][lane][0];
      bf16x8 ah1 = *(const bf16x8*)&g_fc1h[ot][1][lane][0];
      bf16x8 al0 = *(const bf16x8*)&g_fc1l[ot][0][lane][0];
      bf16x8 al1 = *(const bf16x8*)&g_fc1l[ot][1][lane][0];
      f32x4 c4 = {0.f,0.f,0.f,0.f};
      c4 = MFMA16(ah0, bh0, c4, 0,0,0);
      c4 = MFMA16(ah1, bh1, c4, 0,0,0);
      c4 = MFMA16(ah0, bl0, c4, 0,0,0);
      c4 = MFMA16(ah1, bl1, c4, 0,0,0);
      c4 = MFMA16(al0, bh0, c4, 0,0,0);
      c4 = MFMA16(al1, bh1, c4, 0,0,0);
      // C layout: col=kq, row o = ot*16 + g*4 + r
      uint2 rh = *(const uint2*)&Fh[kq*72 + ot*16 + g*4];
      uint2 rl = *(const uint2*)&Fl[kq*72 + ot*16 + g*4];
      float f0 = bf2f((u16)(rh.x&0xffff)) + bf2f((u16)(rl.x&0xffff));
      float f1 = bf2f((u16)(rh.x>>16))    + bf2f((u16)(rl.x>>16));
      float f2q= bf2f((u16)(rh.y&0xffff)) + bf2f((u16)(rl.y&0xffff));
      float f3 = bf2f((u16)(rh.y>>16))    + bf2f((u16)(rl.y>>16));
      float p0 = __expf(fmaxf(c4[0]+fcbv[ot*4+0],0.f));
      float p1 = __expf(fmaxf(c4[1]+fcbv[ot*4+1],0.f));
      float p2 = __expf(fmaxf(c4[2]+fcbv[ot*4+2],0.f));
      float p3 = __expf(fmaxf(c4[3]+fcbv[ot*4+3],0.f));
      float s0=red16_sum(p0), s1=red16_sum(p1), s2=red16_sum(p2), s3=red16_sum(p3);
      float w0=red16_sum(f0*p0), w1=red16_sum(f1*p1), w2q=red16_sum(f2q*p2), w3=red16_sum(f3*p3);
      if (kq==0){
        float a0=__fdividef(w0,s0), a1=__fdividef(w1,s1), a2=__fdividef(w2q,s2), a3=__fdividef(w3,s3);
        u16 h0=f2bf(a0), h1=f2bf(a1), h2=f2bf(a2), h3=f2bf(a3);
        uint2 wh; wh.x=pk2(h0,h1); wh.y=pk2(h2,h3);
        uint2 wl; wl.x=pk2(f2bf(a0-bf2f(h0)), f2bf(a1-bf2f(h1)));
                  wl.y=pk2(f2bf(a2-bf2f(h2)), f2bf(a3-bf2f(h3)));
        *(uint2*)&Agh[t*72 + ot*16 + g*4] = wh;
        *(uint2*)&Agl[t*72 + ot*16 + g*4] = wl;
      }
    }
    wave_sync();
  }
  // phase 2: ap1 (32 outputs) batched over 16 points; B cols = points
  bf16x8 gh0 = *(const bf16x8*)&Agh[kq*72 + 8*g];
  bf16x8 gh1 = *(const bf16x8*)&Agh[kq*72 + 32 + 8*g];
  bf16x8 gl0 = *(const bf16x8*)&Agl[kq*72 + 8*g];
  bf16x8 gl1 = *(const bf16x8*)&Agl[kq*72 + 32 + 8*g];
  #pragma unroll
  for (int ot=0;ot<2;++ot){
    bf16x8 ah0 = *(const bf16x8*)&g_ap1h[ot][0][lane][0];
    bf16x8 ah1 = *(const bf16x8*)&g_ap1h[ot][1][lane][0];
    bf16x8 al0 = *(const bf16x8*)&g_ap1l[ot][0][lane][0];
    bf16x8 al1 = *(const bf16x8*)&g_ap1l[ot][1][lane][0];
    f32x4 c4 = {0.f,0.f,0.f,0.f};
    c4 = MFMA16(ah0, gh0, c4, 0,0,0);
    c4 = MFMA16(ah1, gh1, c4, 0,0,0);
    c4 = MFMA16(ah0, gl0, c4, 0,0,0);
    c4 = MFMA16(ah1, gl1, c4, 0,0,0);
    c4 = MFMA16(al0, gh0, c4, 0,0,0);
    c4 = MFMA16(al1, gh1, c4, 0,0,0);
    #pragma unroll
    for (int r=0;r<4;++r){
      int h = ot*16 + g*4 + r;
      fagg[((size_t)(pn0 + kq))*32 + h] = fmaxf(c4[r] + pcbv[ot*4+r], 0.f);
    }
  }
}

__global__ __launch_bounds__(256,3) void k_stage2(
  const float* __restrict__ xyz, const float* __restrict__ fagg, const int* __restrict__ nidx,
  const float* __restrict__ fcb, float* __restrict__ outp)
{
  __shared__ u16 sFh[4][16*72], sFl[4][16*72];
  __shared__ u16 sXh[4][16*40], sXl[4][16*40];
  __shared__ u16 sAh[4][16*72], sAl[4][16*72];
  int tid=threadIdx.x, lane=tid&63, wv=tid>>6;
  int kq=lane&15, g=lane>>4;
  u16 *Fh=&sFh[wv][0], *Fl=&sFl[wv][0], *Xh=&sXh[wv][0], *Xl=&sXl[wv][0];
  u16 *Agh=&sAh[wv][0], *Agl=&sAl[wv][0];
  int pn0 = (blockIdx.x*4 + wv)*16;
  int b = (pn0 >= NN) ? 1 : 0;
  int base = b*NN;

  float fcbv[16], pdbv[16], b2v[8];
  #pragma unroll
  for (int ot=0;ot<4;++ot)
    #pragma unroll
    for (int r=0;r<4;++r){
      fcbv[ot*4+r] = fcb[ot*16 + g*4 + r];
      pdbv[ot*4+r] = g_pdb[ot*16 + g*4 + r];
    }
  #pragma unroll
  for (int ot=0;ot<2;++ot)
    #pragma unroll
    for (int r=0;r<4;++r) b2v[ot*4+r] = g_pb2[ot*16 + g*4 + r];

  #pragma unroll 1
  for (int t=0;t<16;++t){
    int pn = pn0 + t;
    int idx = nidx[(size_t)pn*KK + kq];
    const float4* fbp = (const float4*)(fagg + ((size_t)(base+idx))*32 + g*8);
    float4 nb0 = fbp[0], nb1 = fbp[1];

    const float* tp = xyz + (size_t)pn*3;
    const float* qp = xyz + (size_t)(base+idx)*3;
    float t0=tp[0],t1=tp[1],t2=tp[2], q0=qp[0],q1=qp[1],q2=qp[2];
    float r0=t0-q0,r1=t1-q1,r2=t2-q2;
    v2f e2[5] = { mk2(sqrtf(r0*r0+r1*r1+r2*r2),r0), mk2(r1,r2), mk2(t0,t1), mk2(t2,q0), mk2(q1,q2) };

    float fx[32];
    #pragma unroll
    for (int h=0;h<32;++h){
      const v2f* wr = (const v2f*)(g_pw1 + h*10);
      v2f a = mk2(g_pb1[h], 0.f);
      #pragma unroll
      for (int c=0;c<5;++c) a = fma2(wr[c], e2[c], a);
      fx[h] = fmaxf(a.x+a.y, 0.f);
    }
    { // stage f_nb (gathered fagg) cols g*8..g*8+7
      float vv[8] = {nb0.x,nb0.y,nb0.z,nb0.w, nb1.x,nb1.y,nb1.z,nb1.w};
      u16 hs[8], ls[8];
      #pragma unroll
      for (int j=0;j<8;++j){ hs[j]=f2bf(vv[j]); ls[j]=f2bf(vv[j]-bf2f(hs[j])); }
      uint4 ph, pl;
      ph.x=pk2(hs[0],hs[1]); ph.y=pk2(hs[2],hs[3]); ph.z=pk2(hs[4],hs[5]); ph.w=pk2(hs[6],hs[7]);
      pl.x=pk2(ls[0],ls[1]); pl.y=pk2(ls[2],ls[3]); pl.z=pk2(ls[4],ls[5]); pl.w=pk2(ls[6],ls[7]);
      *(uint4*)&Fh[kq*72 + g*8] = ph;
      *(uint4*)&Fl[kq*72 + g*8] = pl;
    }
    if (lane < 16){ // stage mlp1 output (mlp2 input) into X
      #pragma unroll
      for (int c4=0;c4<4;++c4){
        u16 hs[8], ls[8];
        #pragma unroll
        for (int j=0;j<8;++j){ float v=fx[c4*8+j]; hs[j]=f2bf(v); ls[j]=f2bf(v-bf2f(hs[j])); }
        uint4 ph, pl;
        ph.x=pk2(hs[0],hs[1]); ph.y=pk2(hs[2],hs[3]); ph.z=pk2(hs[4],hs[5]); ph.w=pk2(hs[6],hs[7]);
        pl.x=pk2(ls[0],ls[1]); pl.y=pk2(ls[2],ls[3]); pl.z=pk2(ls[4],ls[5]); pl.w=pk2(ls[6],ls[7]);
        *(uint4*)&Xh[kq*40 + c4*8] = ph;
        *(uint4*)&Xl[kq*40 + c4*8] = pl;
      }
    }
    wave_sync();
    // mlp2 via MFMA (32x32, K=32) -> F rows 32..63
    {
      bf16x8 xh = *(const bf16x8*)&Xh[kq*40 + 8*g];
      bf16x8 xl = *(const bf16x8*)&Xl[kq*40 + 8*g];
      #pragma unroll
      for (int ot=0;ot<2;++ot){
        bf16x8 ah = *(const bf16x8*)&g_m2h[ot][lane][0];
        bf16x8 al = *(const bf16x8*)&g_m2l[ot][lane][0];
        f32x4 mc = {0.f,0.f,0.f,0.f};
        mc = MFMA16(ah, xh, mc, 0,0,0);
        mc = MFMA16(ah, xl, mc, 0,0,0);
        mc = MFMA16(al, xh, mc, 0,0,0);
        u16 mh[4], mlo[4];
        #pragma unroll
        for (int r=0;r<4;++r){
          float mv = fmaxf(mc[r] + b2v[ot*4+r], 0.f);
          mh[r]=f2bf(mv); mlo[r]=f2bf(mv - bf2f(mh[r]));
        }
        uint2 uh; uh.x=pk2(mh[0],mh[1]); uh.y=pk2(mh[2],mh[3]);
        uint2 ul; ul.x=pk2(mlo[0],mlo[1]); ul.y=pk2(mlo[2],mlo[3]);
        *(uint2*)&Fh[kq*72 + 32 + ot*16 + g*4] = uh;
        *(uint2*)&Fl[kq*72 + 32 + ot*16 + g*4] = ul;
      }
    }
    wave_sync();
    // fc2 + softmax + agg
    bf16x8 bh0 = *(const bf16x8*)&Fh[kq*72 + 8*g];
    bf16x8 bh1 = *(const bf16x8*)&Fh[kq*72 + 32 + 8*g];
    bf16x8 bl0 = *(const bf16x8*)&Fl[kq*72 + 8*g];
    bf16x8 bl1 = *(const bf16x8*)&Fl[kq*72 + 32 + 8*g];
    #pragma unroll
    for (int ot=0;ot<4;++ot){
      bf16x8 ah0 = *(const bf16x8*)&g_fc2h[ot][0][lane][0];
      bf16x8 ah1 = *(const bf16x8*)&g_fc2h[ot][1][lane][0];
      bf16x8 al0 = *(const bf16x8*)&g_fc2l[ot][0][lane][0];
      bf16x8 al1 = *(const bf16x8*)&g_fc2l[ot][1][lane][0];
      f32x4 c4 = {0.f,0.f,0.f,0.f};
      c4 = MFMA16(ah0, bh0, c4, 0,0,0);
      c4 = MFMA16(ah1, bh1, c4, 0,0,0);
      c4 = MFMA16(ah0, bl0, c4, 0,0,0);
      c4 = MFMA16(ah1, bl1, c4, 0,0,0);
      c4 = MFMA16(al0, bh0, c4, 0,0,0);
      c4 = MFMA16(al1, bh1, c4, 0,0,0);
      uint2 rh = *(const uint2*)&Fh[kq*72 + ot*16 + g*4];
      uint2 rl = *(const uint2*)&Fl[kq*72 + ot*16 + g*4];
      float f0 = bf2f((u16)(rh.x&0xffff)) + bf2f((u16)(rl.x&0xffff));
      float f1 = bf2f((u16)(rh.x>>16))    + bf2f((u16)(rl.x>>16));
      float f2q= bf2f((u16)(rh.y&0xffff)) + bf2f((u16)(rl.y&0xffff));
      float f3 = bf2f((u16)(rh.y>>16))    + bf2f((u16)(rl.y>>16));
      float p0 = __expf(fmaxf(c4[0]+fcbv[ot*4+0],0.f));
      float p1 = __expf(fmaxf(c4[1]+fcbv[ot*4+1],0.f));
      float p2 = __expf(fmaxf(c4[2]+fcbv[ot*4+2],0.f));
      float p3 = __expf(fmaxf(c4[3]+fcbv[ot*4+3],0.f));
      float s0=red16_sum(p0), s1=red16_sum(p1), s2=red16_sum(p2), s3=red16_sum(p3);
      float w0=red16_sum(f0*p0), w1=red16_sum(f1*p1), w2q=red16_sum(f2q*p2), w3=red16_sum(f3*p3);
      if (kq==0){
        float a0=__fdividef(w0,s0), a1=__fdividef(w1,s1), a2=__fdividef(w2q,s2), a3=__fdividef(w3,s3);
        u16 h0=f2bf(a0), h1=f2bf(a1), h2=f2bf(a2), h3=f2bf(a3);
        uint2 wh; wh.x=pk2(h0,h1); wh.y=pk2(h2,h3);
        uint2 wl; wl.x=pk2(f2bf(a0-bf2f(h0)), f2bf(a1-bf2f(h1)));
                  wl.y=pk2(f2bf(a2-bf2f(h2)), f2bf(a3-bf2f(h3)));
        *(uint2*)&Agh[t*72 + ot*16 + g*4] = wh;
        *(uint2*)&Agl[t*72 + ot*16 + g*4] = wl;
      }
    }
    wave_sync();
  }
  // phase 2: ap2 (64 outputs) batched over the 16 points; coalesced 64B output rows
  bf16x8 gh0 = *(const bf16x8*)&Agh[kq*72 + 8*g];
  bf16x8 gh1 = *(const bf16x8*)&Agh[kq*72 + 32 + 8*g];
  bf16x8 gl0 = *(const bf16x8*)&Agl[kq*72 + 8*g];
  bf16x8 gl1 = *(const bf16x8*)&Agl[kq*72 + 32 + 8*g];
  int n0l = pn0 - base;
  #pragma unroll
  for (int ot=0;ot<4;++ot){
    bf16x8 ah0 = *(const bf16x8*)&g_ap2h[ot][0][lane][0];
    bf16x8 ah1 = *(const bf16x8*)&g_ap2h[ot][1][lane][0];
    bf16x8 al0 = *(const bf16x8*)&g_ap2l[ot][0][lane][0];
    bf16x8 al1 = *(const bf16x8*)&g_ap2l[ot][1][lane][0];
    f32x4 c4 = {0.f,0.f,0.f,0.f};
    c4 = MFMA16(ah0, gh0, c4, 0,0,0);
    c4 = MFMA16(ah1, gh1, c4, 0,0,0);
    c4 = MFMA16(ah0, gl0, c4, 0,0,0);
    c4 = MFMA16(ah1, gl1, c4, 0,0,0);
    c4 = MFMA16(al0, gh0, c4, 0,0,0);
    c4 = MFMA16(al1, gh1, c4, 0,0,0);
    #pragma unroll
    for (int r=0;r<4;++r){
      int h = ot*16 + g*4 + r;
      outp[((size_t)(b*64 + h))*NN + n0l + kq] = fmaxf(c4[r] + pdbv[ot*4+r], 0.f);
    }
  }
}

extern "C" void kernel_launch(void* const* d_in, const int* in_sizes, int n_in,
                              void* d_out, int out_size, void* d_ws, size_t ws_size,
                              hipStream_t stream){
  const float* xyz     = (const float*)d_in[0];
  const float* feature = (const float*)d_in[1];
  const int*   nidx    = (const int*)d_in[30];
  float* feat_t = (float*)d_ws;                       // (B,N,32)
  float* fagg   = feat_t + (size_t)BB*NN*32;          // (B,N,32)

  k_pre<<<BB*NN/256 + 1, 256, 0, stream>>>(feature, feat_t,
    (const float*)d_in[2],(const float*)d_in[3],(const float*)d_in[4],(const float*)d_in[5],
    (const float*)d_in[6],(const float*)d_in[7],
    (const float*)d_in[8],
    (const float*)d_in[10],(const float*)d_in[11],(const float*)d_in[12],(const float*)d_in[13],
    (const float*)d_in[14],(const float*)d_in[15],
    (const float*)d_in[16],(const float*)d_in[17],(const float*)d_in[18],(const float*)d_in[19],
    (const float*)d_in[20],(const float*)d_in[21],
    (const float*)d_in[22],
    (const float*)d_in[24],(const float*)d_in[25],(const float*)d_in[26],(const float*)d_in[27],
    (const float*)d_in[28],(const float*)d_in[29]);
  // 81920 points / (4 waves x 16 points) = 1280 blocks
  k_stage1<<<BB*NN/64, 256, 0, stream>>>(xyz, feat_t, nidx,
    (const float*)d_in[9], fagg);
  k_stage2<<<BB*NN/64, 256, 0, stream>>>(xyz, fagg, nidx,
    (const float*)d_in[23], (float*)d_out);
}

// Round 11
// 438.271 us; speedup vs baseline: 3.2245x; 1.7203x over previous
//
#include <hip/hip_runtime.h>
#include <math.h>

#define BB 2
#define NN 40960
#define KK 16

typedef float v2f __attribute__((ext_vector_type(2)));
__device__ __forceinline__ v2f fma2(v2f a, v2f b, v2f c){
  return __builtin_elementwise_fma(a, b, c);
}
__device__ __forceinline__ v2f mk2(float a, float b){ v2f r; r.x=a; r.y=b; return r; }

// ---- 16-lane sum on the VALU pipe via DPP ----
template<int CTRL>
__device__ __forceinline__ float dppf(float x){
  return __int_as_float(__builtin_amdgcn_update_dpp(0, __float_as_int(x), CTRL, 0xF, 0xF, true));
}
__device__ __forceinline__ float red16_sum(float v){
  v += dppf<0xB1>(v);    // quad_perm:[1,0,3,2]  (xor 1)
  v += dppf<0x4E>(v);    // quad_perm:[2,3,0,1]  (xor 2)
  v += dppf<0x141>(v);   // row_half_mirror      (xor 4 equiv)
  v += dppf<0x140>(v);   // row_mirror           (xor 8 equiv)
  return v;
}

// ---- BN-folded weights, computed once (30.6 KB) ----
__device__ alignas(16) float g_pw1[32*10];
__device__ alignas(16) float g_pb1[32];
__device__ alignas(16) float g_pw2[32*32];
__device__ alignas(16) float g_pb2[32];
__device__ alignas(16) float g_pcw[32*64];   // ap1 mlp folded
__device__ alignas(16) float g_pcb[32];
__device__ alignas(16) float g_pdw[64*64];   // ap2 mlp folded
__device__ alignas(16) float g_pdb[64];

// Fused: feature transpose (blocks 0..319) + BN-fold prep (last block)
__global__ __launch_bounds__(256) void k_pre(
  const float* __restrict__ feat, float* __restrict__ feat_t,
  const float* __restrict__ w1, const float* __restrict__ b1,
  const float* __restrict__ g1, const float* __restrict__ be1, const float* __restrict__ m1, const float* __restrict__ v1,
  const float* __restrict__ w2, const float* __restrict__ b2,
  const float* __restrict__ g2, const float* __restrict__ be2, const float* __restrict__ m2, const float* __restrict__ v2,
  const float* __restrict__ cw, const float* __restrict__ cb,
  const float* __restrict__ cg, const float* __restrict__ cbe, const float* __restrict__ cm, const float* __restrict__ cv,
  const float* __restrict__ dw, const float* __restrict__ db,
  const float* __restrict__ dg, const float* __restrict__ dbe, const float* __restrict__ dm, const float* __restrict__ dv)
{
  int tid = threadIdx.x;
  int bid = blockIdx.x;
  if (bid < BB*NN/256){
    int b = bid / (NN/256);
    int n = (bid % (NN/256))*256 + tid;
    float v[32];
    #pragma unroll
    for (int h=0; h<32; ++h) v[h] = feat[((size_t)(b*32+h))*NN + n];
    float* o = feat_t + ((size_t)b*NN + n)*32;
    #pragma unroll
    for (int h=0; h<32; h+=4){ *(float4*)(o+h) = make_float4(v[h],v[h+1],v[h+2],v[h+3]); }
    return;
  }
  for (int i=tid; i<320; i+=256){ int h=i/10;
    g_pw1[i] = w1[i] * (g1[h]*rsqrtf(v1[h]+1e-5f)); }
  if (tid<32){ float s=g1[tid]*rsqrtf(v1[tid]+1e-5f);
    g_pb1[tid] = (b1[tid]-m1[tid])*s+be1[tid]; }
  for (int i=tid; i<1024; i+=256){ int h=i>>5;
    g_pw2[i] = w2[i] * (g2[h]*rsqrtf(v2[h]+1e-5f)); }
  if (tid<32){ float s=g2[tid]*rsqrtf(v2[tid]+1e-5f);
    g_pb2[tid] = (b2[tid]-m2[tid])*s+be2[tid]; }
  for (int i=tid; i<2048; i+=256){ int h=i>>6;
    g_pcw[i] = cw[i] * (cg[h]*rsqrtf(cv[h]+1e-5f)); }
  if (tid<32){ float s=cg[tid]*rsqrtf(cv[tid]+1e-5f);
    g_pcb[tid] = (cb[tid]-cm[tid])*s+cbe[tid]; }
  for (int i=tid; i<4096; i+=256){ int h=i>>6;
    g_pdw[i] = dw[i] * (dg[h]*rsqrtf(dv[h]+1e-5f)); }
  if (tid<64){ float s=dg[tid]*rsqrtf(dv[tid]+1e-5f);
    g_pdb[tid] = (db[tid]-dm[tid])*s+dbe[tid]; }
}

__global__ __launch_bounds__(256,2) void k_stage1(
  const float* __restrict__ xyz, const float* __restrict__ feat_t, const int* __restrict__ nidx,
  const float* __restrict__ fcw, const float* __restrict__ fcb,
  float* __restrict__ fagg)
{
  int tid = threadIdx.x;
  int lane = tid & 63, wvv = tid >> 6;
  int k = lane & 15, ns = lane >> 4;
  int b = blockIdx.x / (NN/16);
  int n = (blockIdx.x % (NN/16))*16 + wvv*4 + ns;
  size_t bn = (size_t)b*NN + n;
  int idxv = nidx[bn*KK + k];

  // scattered gathers first; latency hides under mlp1
  alignas(16) float fc_[64];
  const float* fb = feat_t + ((size_t)b*NN + idxv)*32;
  #pragma unroll
  for (int h=0; h<32; h+=4){ float4 x=*(const float4*)(fb+h);
    fc_[h]=x.x; fc_[h+1]=x.y; fc_[h+2]=x.z; fc_[h+3]=x.w; }

  const float* tp = xyz + bn*3;
  const float* qp = xyz + ((size_t)b*NN + idxv)*3;
  float t0=tp[0],t1=tp[1],t2=tp[2];
  float q0=qp[0],q1=qp[1],q2=qp[2];
  float r0=t0-q0,r1=t1-q1,r2=t2-q2;
  v2f e2[5] = { {sqrtf(r0*r0+r1*r1+r2*r2), r0}, {r1,r2}, {t0,t1}, {t2,q0}, {q1,q2} };

  // mlp1 (10->32, BN pre-folded, relu)
  #pragma unroll
  for (int h=0; h<32; ++h){
    const v2f* wr = (const v2f*)(g_pw1 + h*10);
    v2f acc = mk2(g_pb1[h], 0.f);
    #pragma unroll
    for (int c=0; c<5; ++c) acc = fma2(wr[c], e2[c], acc);
    fc_[32+h] = fmaxf(acc.x+acc.y, 0.f);
  }

  // fc1 (64->64) + relu + softmax over K + weighted agg — channel QUADS:
  // all 4 channels of a quad belong to the same owner lane (ob>>2 const).
  const v2f* fv = (const v2f*)fc_;
  float sp4[4], sf4[4];
  #pragma unroll
  for (int ob=0; ob<64; ob+=4){
    const v2f* w0 = (const v2f*)(fcw + ob*64);
    const v2f* w1p = (const v2f*)(fcw + (ob+1)*64);
    const v2f* w2p = (const v2f*)(fcw + (ob+2)*64);
    const v2f* w3p = (const v2f*)(fcw + (ob+3)*64);
    v2f a0=mk2(fcb[ob],0.f), a1=mk2(fcb[ob+1],0.f), a2=mk2(fcb[ob+2],0.f), a3=mk2(fcb[ob+3],0.f);
    #pragma unroll
    for (int c=0; c<32; ++c){
      v2f f = fv[c];
      a0 = fma2(w0[c], f, a0); a1 = fma2(w1p[c], f, a1);
      a2 = fma2(w2p[c], f, a2); a3 = fma2(w3p[c], f, a3);
    }
    float l0=fmaxf(a0.x+a0.y,0.f), l1=fmaxf(a1.x+a1.y,0.f);
    float l2=fmaxf(a2.x+a2.y,0.f), l3=fmaxf(a3.x+a3.y,0.f);
    float p0=__expf(l0), p1=__expf(l1), p2=__expf(l2), p3=__expf(l3);
    float q0v=fc_[ob]*p0, q1v=fc_[ob+1]*p1, q2v=fc_[ob+2]*p2, q3v=fc_[ob+3]*p3;
    float s0=red16_sum(p0), s1=red16_sum(p1), s2=red16_sum(p2), s3=red16_sum(p3);
    float t0v=red16_sum(q0v), t1v=red16_sum(q1v), t2v=red16_sum(q2v), t3v=red16_sum(q3v);
    if ((ob>>2)==k){
      sp4[0]=s0; sp4[1]=s1; sp4[2]=s2; sp4[3]=s3;
      sf4[0]=t0v; sf4[1]=t1v; sf4[2]=t2v; sf4[3]=t3v;
    }
  }
  v2f a01 = mk2(__fdividef(sf4[0],sp4[0]), __fdividef(sf4[1],sp4[1]));
  v2f a23 = mk2(__fdividef(sf4[2],sp4[2]), __fdividef(sf4[3],sp4[3]));

  // ap1 mlp (64->32, BN pre-folded, relu) — h pairs for ILP
  float o0=0.f, o1=0.f;
  #pragma unroll
  for (int h=0; h<32; h+=2){
    const v2f* wr0 = (const v2f*)(g_pcw + h*64 + 4*k);
    const v2f* wr1 = (const v2f*)(g_pcw + (h+1)*64 + 4*k);
    v2f p0 = fma2(wr0[0], a01, wr0[1]*a23);
    v2f p1 = fma2(wr1[0], a01, wr1[1]*a23);
    float r0v = red16_sum(p0.x + p0.y);
    float r1v = red16_sum(p1.x + p1.y);
    float v0 = fmaxf(r0v + g_pcb[h], 0.f);
    float v1 = fmaxf(r1v + g_pcb[h+1], 0.f);
    if ((h&15)==k){ if (h<16) o0=v0; else o1=v0; }
    if (((h+1)&15)==k){ if (h+1<16) o0=v1; else o1=v1; }
  }
  float* fo = fagg + bn*32;
  fo[k]=o0; fo[k+16]=o1;
}

__global__ __launch_bounds__(256,2) void k_stage2(
  const float* __restrict__ xyz, const float* __restrict__ fagg, const int* __restrict__ nidx,
  const float* __restrict__ fcw, const float* __restrict__ fcb,
  float* __restrict__ outp)
{
  int tid = threadIdx.x;
  int lane = tid & 63, wvv = tid >> 6;
  int k = lane & 15, ns = lane >> 4;
  int b = blockIdx.x / (NN/16);
  int n = (blockIdx.x % (NN/16))*16 + wvv*4 + ns;
  size_t bn = (size_t)b*NN + n;
  int idxv = nidx[bn*KK + k];

  // scattered gather first; latency hides under mlp1+mlp2
  alignas(16) float fc_[64];
  const float* fb = fagg + ((size_t)b*NN + idxv)*32;
  #pragma unroll
  for (int h=0; h<32; h+=4){ float4 x=*(const float4*)(fb+h);
    fc_[h]=x.x; fc_[h+1]=x.y; fc_[h+2]=x.z; fc_[h+3]=x.w; }

  const float* tp = xyz + bn*3;
  const float* qp = xyz + ((size_t)b*NN + idxv)*3;
  float t0=tp[0],t1=tp[1],t2=tp[2];
  float q0=qp[0],q1=qp[1],q2=qp[2];
  float r0=t0-q0,r1=t1-q1,r2=t2-q2;
  v2f e2[5] = { {sqrtf(r0*r0+r1*r1+r2*r2), r0}, {r1,r2}, {t0,t1}, {t2,q0}, {q1,q2} };

  // recompute f_xyz (mlp1)
  alignas(8) float fx[32];
  #pragma unroll
  for (int h=0; h<32; ++h){
    const v2f* wr = (const v2f*)(g_pw1 + h*10);
    v2f acc = mk2(g_pb1[h], 0.f);
    #pragma unroll
    for (int c=0; c<5; ++c) acc = fma2(wr[c], e2[c], acc);
    fx[h] = fmaxf(acc.x+acc.y, 0.f);
  }

  // mlp2 (32->32, BN pre-folded, relu)
  const v2f* fxv = (const v2f*)fx;
  #pragma unroll
  for (int h=0; h<32; ++h){
    const v2f* wr = (const v2f*)(g_pw2 + h*32);
    v2f acc = mk2(g_pb2[h], 0.f);
    #pragma unroll
    for (int c=0; c<16; ++c) acc = fma2(wr[c], fxv[c], acc);
    fc_[32+h] = fmaxf(acc.x+acc.y, 0.f);
  }

  // fc2 + relu + softmax over K + weighted agg — channel quads
  const v2f* fv = (const v2f*)fc_;
  float sp4[4], sf4[4];
  #pragma unroll
  for (int ob=0; ob<64; ob+=4){
    const v2f* w0 = (const v2f*)(fcw + ob*64);
    const v2f* w1p = (const v2f*)(fcw + (ob+1)*64);
    const v2f* w2p = (const v2f*)(fcw + (ob+2)*64);
    const v2f* w3p = (const v2f*)(fcw + (ob+3)*64);
    v2f a0=mk2(fcb[ob],0.f), a1=mk2(fcb[ob+1],0.f), a2=mk2(fcb[ob+2],0.f), a3=mk2(fcb[ob+3],0.f);
    #pragma unroll
    for (int c=0; c<32; ++c){
      v2f f = fv[c];
      a0 = fma2(w0[c], f, a0); a1 = fma2(w1p[c], f, a1);
      a2 = fma2(w2p[c], f, a2); a3 = fma2(w3p[c], f, a3);
    }
    float l0=fmaxf(a0.x+a0.y,0.f), l1=fmaxf(a1.x+a1.y,0.f);
    float l2=fmaxf(a2.x+a2.y,0.f), l3=fmaxf(a3.x+a3.y,0.f);
    float p0=__expf(l0), p1=__expf(l1), p2=__expf(l2), p3=__expf(l3);
    float q0v=fc_[ob]*p0, q1v=fc_[ob+1]*p1, q2v=fc_[ob+2]*p2, q3v=fc_[ob+3]*p3;
    float s0=red16_sum(p0), s1=red16_sum(p1), s2=red16_sum(p2), s3=red16_sum(p3);
    float t0v=red16_sum(q0v), t1v=red16_sum(q1v), t2v=red16_sum(q2v), t3v=red16_sum(q3v);
    if ((ob>>2)==k){
      sp4[0]=s0; sp4[1]=s1; sp4[2]=s2; sp4[3]=s3;
      sf4[0]=t0v; sf4[1]=t1v; sf4[2]=t2v; sf4[3]=t3v;
    }
  }
  v2f a01 = mk2(__fdividef(sf4[0],sp4[0]), __fdividef(sf4[1],sp4[1]));
  v2f a23 = mk2(__fdividef(sf4[2],sp4[2]), __fdividef(sf4[3],sp4[3]));

  // ap2 mlp (64->64, BN pre-folded, relu) -> output — h pairs for ILP
  float o4[4];
  #pragma unroll
  for (int h=0; h<64; h+=2){
    const v2f* wr0 = (const v2f*)(g_pdw + h*64 + 4*k);
    const v2f* wr1 = (const v2f*)(g_pdw + (h+1)*64 + 4*k);
    v2f p0 = fma2(wr0[0], a01, wr0[1]*a23);
    v2f p1 = fma2(wr1[0], a01, wr1[1]*a23);
    float r0v = red16_sum(p0.x + p0.y);
    float r1v = red16_sum(p1.x + p1.y);
    float v0 = fmaxf(r0v + g_pdb[h], 0.f);
    float v1 = fmaxf(r1v + g_pdb[h+1], 0.f);
    if ((h&15)==k) o4[h>>4] = v0;
    if (((h+1)&15)==k) o4[(h+1)>>4] = v1;
  }
  #pragma unroll
  for (int j=0; j<4; ++j)
    outp[((size_t)(b*64 + k + 16*j))*NN + n] = o4[j];
}

extern "C" void kernel_launch(void* const* d_in, const int* in_sizes, int n_in,
                              void* d_out, int out_size, void* d_ws, size_t ws_size,
                              hipStream_t stream){
  const float* xyz     = (const float*)d_in[0];
  const float* feature = (const float*)d_in[1];
  const int*   nidx    = (const int*)d_in[30];
  float* feat_t = (float*)d_ws;                       // (B,N,32)
  float* fagg   = feat_t + (size_t)BB*NN*32;          // (B,N,32)

  k_pre<<<BB*NN/256 + 1, 256, 0, stream>>>(feature, feat_t,
    (const float*)d_in[2],(const float*)d_in[3],(const float*)d_in[4],(const float*)d_in[5],
    (const float*)d_in[6],(const float*)d_in[7],
    (const float*)d_in[16],(const float*)d_in[17],(const float*)d_in[18],(const float*)d_in[19],
    (const float*)d_in[20],(const float*)d_in[21],
    (const float*)d_in[10],(const float*)d_in[11],(const float*)d_in[12],(const float*)d_in[13],
    (const float*)d_in[14],(const float*)d_in[15],
    (const float*)d_in[24],(const float*)d_in[25],(const float*)d_in[26],(const float*)d_in[27],
    (const float*)d_in[28],(const float*)d_in[29]);
  k_stage1<<<BB*NN/16, 256, 0, stream>>>(xyz, feat_t, nidx,
    (const float*)d_in[8],(const float*)d_in[9], fagg);
  k_stage2<<<BB*NN/16, 256, 0, stream>>>(xyz, fagg, nidx,
    (const float*)d_in[22],(const float*)d_in[23], (float*)d_out);
}

// Round 13
// 426.502 us; speedup vs baseline: 3.3134x; 1.0276x over previous
//
#include <hip/hip_runtime.h>
#include <math.h>

#define BB 2
#define NN 40960
#define KK 16

typedef float v2f __attribute__((ext_vector_type(2)));
typedef _Float16 h16;
typedef h16 h16x2 __attribute__((ext_vector_type(2)));

__device__ __forceinline__ v2f fma2(v2f a, v2f b, v2f c){
  return __builtin_elementwise_fma(a, b, c);
}
__device__ __forceinline__ v2f mk2(float a, float b){ v2f r; r.x=a; r.y=b; return r; }

#if __has_builtin(__builtin_amdgcn_fdot2)
__device__ __forceinline__ float dot2acc(h16x2 w, h16x2 f, float acc){
  return __builtin_amdgcn_fdot2(w, f, acc, false);
}
#else
__device__ __forceinline__ float dot2acc(h16x2 w, h16x2 f, float acc){
  return acc + (float)w.x*(float)f.x + (float)w.y*(float)f.y;
}
#endif
#if __has_builtin(__builtin_amdgcn_exp2f)
__device__ __forceinline__ float exp2fast(float x){ return __builtin_amdgcn_exp2f(x); }
#else
__device__ __forceinline__ float exp2fast(float x){ return __expf(x*0.6931471805599453f); }
#endif
#if __has_builtin(__builtin_amdgcn_cvt_pkrtz)
__device__ __forceinline__ h16x2 pkh(float a, float b){
  return __builtin_bit_cast(h16x2, __builtin_amdgcn_cvt_pkrtz(a,b));
}
#else
__device__ __forceinline__ h16x2 pkh(float a, float b){ h16x2 r; r.x=(h16)a; r.y=(h16)b; return r; }
#endif

// ---- 16-lane sum on the VALU pipe via DPP ----
template<int CTRL>
__device__ __forceinline__ float dppf(float x){
  return __int_as_float(__builtin_amdgcn_update_dpp(0, __float_as_int(x), CTRL, 0xF, 0xF, true));
}
__device__ __forceinline__ float red16_sum(float v){
  v += dppf<0xB1>(v);    // quad_perm:[1,0,3,2]  (xor 1)
  v += dppf<0x4E>(v);    // quad_perm:[2,3,0,1]  (xor 2)
  v += dppf<0x141>(v);   // row_half_mirror      (xor 4 equiv)
  v += dppf<0x140>(v);   // row_mirror           (xor 8 equiv)
  return v;
}

// ---- pre-processed weights (f16 for dot2 paths, f32 elsewhere) ----
__device__ alignas(16) float g_pw1[32*10];
__device__ alignas(16) float g_pb1[32];
__device__ alignas(16) h16x2 g_w2h[32*16];   // mlp2 folded, f16 pairs
__device__ alignas(16) float g_pb2[32];
__device__ alignas(16) h16x2 g_fch1[64*32];  // fc1 * log2e, f16 pairs
__device__ alignas(16) float g_fcb1s[64];    // fc1 bias * log2e
__device__ alignas(16) h16x2 g_fch2[64*32];  // fc2 * log2e, f16 pairs
__device__ alignas(16) float g_fcb2s[64];
__device__ alignas(16) float g_pcw[32*64];   // ap1 mlp folded (f32)
__device__ alignas(16) float g_pcb[32];
__device__ alignas(16) float g_pdw[64*64];   // ap2 mlp folded (f32)
__device__ alignas(16) float g_pdb[64];

#define LOG2E 1.44269504088896f

// Fused: feature transpose (blocks 0..319) + weight prep (last block)
__global__ __launch_bounds__(256) void k_pre(
  const float* __restrict__ feat, float* __restrict__ feat_t,
  const float* __restrict__ w1, const float* __restrict__ b1,
  const float* __restrict__ g1, const float* __restrict__ be1, const float* __restrict__ m1, const float* __restrict__ v1,
  const float* __restrict__ fc1w, const float* __restrict__ fc1b,
  const float* __restrict__ cw, const float* __restrict__ cb,
  const float* __restrict__ cg, const float* __restrict__ cbe, const float* __restrict__ cm, const float* __restrict__ cv,
  const float* __restrict__ w2, const float* __restrict__ b2,
  const float* __restrict__ g2, const float* __restrict__ be2, const float* __restrict__ m2, const float* __restrict__ v2,
  const float* __restrict__ fc2w, const float* __restrict__ fc2b,
  const float* __restrict__ dw, const float* __restrict__ db,
  const float* __restrict__ dg, const float* __restrict__ dbe, const float* __restrict__ dm, const float* __restrict__ dv)
{
  int tid = threadIdx.x;
  int bid = blockIdx.x;
  if (bid < BB*NN/256){
    int b = bid / (NN/256);
    int n = (bid % (NN/256))*256 + tid;
    float v[32];
    #pragma unroll
    for (int h=0; h<32; ++h) v[h] = feat[((size_t)(b*32+h))*NN + n];
    float* o = feat_t + ((size_t)b*NN + n)*32;
    #pragma unroll
    for (int h=0; h<32; h+=4){ *(float4*)(o+h) = make_float4(v[h],v[h+1],v[h+2],v[h+3]); }
    return;
  }
  for (int i=tid; i<320; i+=256){ int h=i/10;
    g_pw1[i] = w1[i] * (g1[h]*rsqrtf(v1[h]+1e-5f)); }
  if (tid<32){ float s=g1[tid]*rsqrtf(v1[tid]+1e-5f);
    g_pb1[tid] = (b1[tid]-m1[tid])*s+be1[tid]; }
  // mlp2 folded -> f16 pairs
  for (int i=tid; i<512; i+=256){ int h=i>>4, c=i&15;
    float s=g2[h]*rsqrtf(v2[h]+1e-5f);
    g_w2h[i] = pkh(w2[h*32+2*c]*s, w2[h*32+2*c+1]*s); }
  if (tid<32){ float s=g2[tid]*rsqrtf(v2[tid]+1e-5f);
    g_pb2[tid] = (b2[tid]-m2[tid])*s+be2[tid]; }
  // fc1 / fc2 scaled by log2e -> f16 pairs
  for (int i=tid; i<2048; i+=256){ int o=i>>5, c=i&31;
    g_fch1[i] = pkh(fc1w[o*64+2*c]*LOG2E, fc1w[o*64+2*c+1]*LOG2E);
    g_fch2[i] = pkh(fc2w[o*64+2*c]*LOG2E, fc2w[o*64+2*c+1]*LOG2E); }
  if (tid<64){ g_fcb1s[tid] = fc1b[tid]*LOG2E; g_fcb2s[tid] = fc2b[tid]*LOG2E; }
  for (int i=tid; i<2048; i+=256){ int h=i>>6;
    g_pcw[i] = cw[i] * (cg[h]*rsqrtf(cv[h]+1e-5f)); }
  if (tid<32){ float s=cg[tid]*rsqrtf(cv[tid]+1e-5f);
    g_pcb[tid] = (cb[tid]-cm[tid])*s+cbe[tid]; }
  for (int i=tid; i<4096; i+=256){ int h=i>>6;
    g_pdw[i] = dw[i] * (dg[h]*rsqrtf(dv[h]+1e-5f)); }
  if (tid<64){ float s=dg[tid]*rsqrtf(dv[tid]+1e-5f);
    g_pdb[tid] = (db[tid]-dm[tid])*s+dbe[tid]; }
}

__global__ __launch_bounds__(256,2) void k_stage1(
  const float* __restrict__ xyz, const float* __restrict__ feat_t, const int* __restrict__ nidx,
  float* __restrict__ fagg)
{
  int tid = threadIdx.x;
  int lane = tid & 63, wvv = tid >> 6;
  int k = lane & 15, ns = lane >> 4;
  int b = blockIdx.x / (NN/16);
  int n = (blockIdx.x % (NN/16))*16 + wvv*4 + ns;
  size_t bn = (size_t)b*NN + n;
  int idxv = nidx[bn*KK + k];

  // scattered gathers first; latency hides under mlp1
  alignas(16) float fc_[64];
  const float* fb = feat_t + ((size_t)b*NN + idxv)*32;
  #pragma unroll
  for (int h=0; h<32; h+=4){ float4 x=*(const float4*)(fb+h);
    fc_[h]=x.x; fc_[h+1]=x.y; fc_[h+2]=x.z; fc_[h+3]=x.w; }

  const float* tp = xyz + bn*3;
  const float* qp = xyz + ((size_t)b*NN + idxv)*3;
  float t0=tp[0],t1=tp[1],t2=tp[2];
  float q0=qp[0],q1=qp[1],q2=qp[2];
  float r0=t0-q0,r1=t1-q1,r2=t2-q2;
  v2f e2[5] = { {sqrtf(r0*r0+r1*r1+r2*r2), r0}, {r1,r2}, {t0,t1}, {t2,q0}, {q1,q2} };

  // mlp1 (10->32, BN pre-folded, relu) — fp32
  #pragma unroll
  for (int h=0; h<32; ++h){
    const v2f* wr = (const v2f*)(g_pw1 + h*10);
    v2f acc = mk2(g_pb1[h], 0.f);
    #pragma unroll
    for (int c=0; c<5; ++c) acc = fma2(wr[c], e2[c], acc);
    fc_[32+h] = fmaxf(acc.x+acc.y, 0.f);
  }

  // convert features to f16 pairs for dot2
  h16x2 h2[32];
  #pragma unroll
  for (int c=0; c<32; ++c) h2[c] = pkh(fc_[2*c], fc_[2*c+1]);

  // fc1 (64->64 via dot2, weights*log2e) + relu + exp2-softmax over K + agg
  float sp4[4], sf4[4];
  #pragma unroll
  for (int ob=0; ob<64; ob+=4){
    const h16x2* w0 = &g_fch1[(ob+0)*32];
    const h16x2* w1p = &g_fch1[(ob+1)*32];
    const h16x2* w2p = &g_fch1[(ob+2)*32];
    const h16x2* w3p = &g_fch1[(ob+3)*32];
    float a0=g_fcb1s[ob+0], a1=g_fcb1s[ob+1], a2=g_fcb1s[ob+2], a3=g_fcb1s[ob+3];
    #pragma unroll
    for (int c=0; c<32; ++c){
      h16x2 f = h2[c];
      a0 = dot2acc(w0[c], f, a0); a1 = dot2acc(w1p[c], f, a1);
      a2 = dot2acc(w2p[c], f, a2); a3 = dot2acc(w3p[c], f, a3);
    }
    float p0=exp2fast(fmaxf(a0,0.f)), p1=exp2fast(fmaxf(a1,0.f));
    float p2=exp2fast(fmaxf(a2,0.f)), p3=exp2fast(fmaxf(a3,0.f));
    float f0=(float)h2[(ob>>1)+0].x, f1=(float)h2[(ob>>1)+0].y;
    float f2=(float)h2[(ob>>1)+1].x, f3=(float)h2[(ob>>1)+1].y;
    float q0v=f0*p0, q1v=f1*p1, q2v=f2*p2, q3v=f3*p3;
    float s0=red16_sum(p0), s1=red16_sum(p1), s2=red16_sum(p2), s3=red16_sum(p3);
    float t0v=red16_sum(q0v), t1v=red16_sum(q1v), t2v=red16_sum(q2v), t3v=red16_sum(q3v);
    if ((ob>>2)==k){
      sp4[0]=s0; sp4[1]=s1; sp4[2]=s2; sp4[3]=s3;
      sf4[0]=t0v; sf4[1]=t1v; sf4[2]=t2v; sf4[3]=t3v;
    }
  }
  v2f a01 = mk2(__fdividef(sf4[0],sp4[0]), __fdividef(sf4[1],sp4[1]));
  v2f a23 = mk2(__fdividef(sf4[2],sp4[2]), __fdividef(sf4[3],sp4[3]));

  // ap1 mlp (64->32, BN pre-folded, relu) — fp32, h pairs for ILP
  float o0=0.f, o1=0.f;
  #pragma unroll
  for (int h=0; h<32; h+=2){
    const v2f* wr0 = (const v2f*)(g_pcw + h*64 + 4*k);
    const v2f* wr1 = (const v2f*)(g_pcw + (h+1)*64 + 4*k);
    v2f p0 = fma2(wr0[0], a01, wr0[1]*a23);
    v2f p1 = fma2(wr1[0], a01, wr1[1]*a23);
    float r0v = red16_sum(p0.x + p0.y);
    float r1v = red16_sum(p1.x + p1.y);
    float v0 = fmaxf(r0v + g_pcb[h], 0.f);
    float v1 = fmaxf(r1v + g_pcb[h+1], 0.f);
    if ((h&15)==k){ if (h<16) o0=v0; else o1=v0; }
    if (((h+1)&15)==k){ if (h+1<16) o0=v1; else o1=v1; }
  }
  float* fo = fagg + bn*32;
  fo[k]=o0; fo[k+16]=o1;
}

__global__ __launch_bounds__(256,2) void k_stage2(
  const float* __restrict__ xyz, const float* __restrict__ fagg, const int* __restrict__ nidx,
  float* __restrict__ outp)
{
  int tid = threadIdx.x;
  int lane = tid & 63, wvv = tid >> 6;
  int k = lane & 15, ns = lane >> 4;
  int b = blockIdx.x / (NN/16);
  int n = (blockIdx.x % (NN/16))*16 + wvv*4 + ns;
  size_t bn = (size_t)b*NN + n;
  int idxv = nidx[bn*KK + k];

  // scattered gather first; latency hides under mlp1+mlp2
  alignas(16) float fc_[64];
  const float* fb = fagg + ((size_t)b*NN + idxv)*32;
  #pragma unroll
  for (int h=0; h<32; h+=4){ float4 x=*(const float4*)(fb+h);
    fc_[h]=x.x; fc_[h+1]=x.y; fc_[h+2]=x.z; fc_[h+3]=x.w; }

  const float* tp = xyz + bn*3;
  const float* qp = xyz + ((size_t)b*NN + idxv)*3;
  float t0=tp[0],t1=tp[1],t2=tp[2];
  float q0=qp[0],q1=qp[1],q2=qp[2];
  float r0=t0-q0,r1=t1-q1,r2=t2-q2;
  v2f e2[5] = { {sqrtf(r0*r0+r1*r1+r2*r2), r0}, {r1,r2}, {t0,t1}, {t2,q0}, {q1,q2} };

  // recompute f_xyz (mlp1) — fp32
  alignas(8) float fx[32];
  #pragma unroll
  for (int h=0; h<32; ++h){
    const v2f* wr = (const v2f*)(g_pw1 + h*10);
    v2f acc = mk2(g_pb1[h], 0.f);
    #pragma unroll
    for (int c=0; c<5; ++c) acc = fma2(wr[c], e2[c], acc);
    fx[h] = fmaxf(acc.x+acc.y, 0.f);
  }
  // mlp2 (32->32) via dot2
  h16x2 hx[16];
  #pragma unroll
  for (int c=0; c<16; ++c) hx[c] = pkh(fx[2*c], fx[2*c+1]);
  #pragma unroll
  for (int h=0; h<32; h+=2){
    const h16x2* wr0 = &g_w2h[(h+0)*16];
    const h16x2* wr1 = &g_w2h[(h+1)*16];
    float a0 = g_pb2[h+0], a1 = g_pb2[h+1];
    #pragma unroll
    for (int c=0; c<16; ++c){ h16x2 f=hx[c]; a0=dot2acc(wr0[c],f,a0); a1=dot2acc(wr1[c],f,a1); }
    fc_[32+h]   = fmaxf(a0, 0.f);
    fc_[32+h+1] = fmaxf(a1, 0.f);
  }

  // convert features to f16 pairs
  h16x2 h2[32];
  #pragma unroll
  for (int c=0; c<32; ++c) h2[c] = pkh(fc_[2*c], fc_[2*c+1]);

  // fc2 via dot2 + exp2-softmax + agg
  float sp4[4], sf4[4];
  #pragma unroll
  for (int ob=0; ob<64; ob+=4){
    const h16x2* w0 = &g_fch2[(ob+0)*32];
    const h16x2* w1p = &g_fch2[(ob+1)*32];
    const h16x2* w2p = &g_fch2[(ob+2)*32];
    const h16x2* w3p = &g_fch2[(ob+3)*32];
    float a0=g_fcb2s[ob+0], a1=g_fcb2s[ob+1], a2=g_fcb2s[ob+2], a3=g_fcb2s[ob+3];
    #pragma unroll
    for (int c=0; c<32; ++c){
      h16x2 f = h2[c];
      a0 = dot2acc(w0[c], f, a0); a1 = dot2acc(w1p[c], f, a1);
      a2 = dot2acc(w2p[c], f, a2); a3 = dot2acc(w3p[c], f, a3);
    }
    float p0=exp2fast(fmaxf(a0,0.f)), p1=exp2fast(fmaxf(a1,0.f));
    float p2=exp2fast(fmaxf(a2,0.f)), p3=exp2fast(fmaxf(a3,0.f));
    float f0=(float)h2[(ob>>1)+0].x, f1=(float)h2[(ob>>1)+0].y;
    float f2=(float)h2[(ob>>1)+1].x, f3=(float)h2[(ob>>1)+1].y;
    float q0v=f0*p0, q1v=f1*p1, q2v=f2*p2, q3v=f3*p3;
    float s0=red16_sum(p0), s1=red16_sum(p1), s2=red16_sum(p2), s3=red16_sum(p3);
    float t0v=red16_sum(q0v), t1v=red16_sum(q1v), t2v=red16_sum(q2v), t3v=red16_sum(q3v);
    if ((ob>>2)==k){
      sp4[0]=s0; sp4[1]=s1; sp4[2]=s2; sp4[3]=s3;
      sf4[0]=t0v; sf4[1]=t1v; sf4[2]=t2v; sf4[3]=t3v;
    }
  }
  v2f a01 = mk2(__fdividef(sf4[0],sp4[0]), __fdividef(sf4[1],sp4[1]));
  v2f a23 = mk2(__fdividef(sf4[2],sp4[2]), __fdividef(sf4[3],sp4[3]));

  // ap2 mlp (64->64, BN pre-folded, relu) -> output — fp32, h pairs for ILP
  float o4[4];
  #pragma unroll
  for (int h=0; h<64; h+=2){
    const v2f* wr0 = (const v2f*)(g_pdw + h*64 + 4*k);
    const v2f* wr1 = (const v2f*)(g_pdw + (h+1)*64 + 4*k);
    v2f p0 = fma2(wr0[0], a01, wr0[1]*a23);
    v2f p1 = fma2(wr1[0], a01, wr1[1]*a23);
    float r0v = red16_sum(p0.x + p0.y);
    float r1v = red16_sum(p1.x + p1.y);
    float v0 = fmaxf(r0v + g_pdb[h], 0.f);
    float v1 = fmaxf(r1v + g_pdb[h+1], 0.f);
    if ((h&15)==k) o4[h>>4] = v0;
    if (((h+1)&15)==k) o4[(h+1)>>4] = v1;
  }
  #pragma unroll
  for (int j=0; j<4; ++j)
    outp[((size_t)(b*64 + k + 16*j))*NN + n] = o4[j];
}

extern "C" void kernel_launch(void* const* d_in, const int* in_sizes, int n_in,
                              void* d_out, int out_size, void* d_ws, size_t ws_size,
                              hipStream_t stream){
  const float* xyz     = (const float*)d_in[0];
  const float* feature = (const float*)d_in[1];
  const int*   nidx    = (const int*)d_in[30];
  float* feat_t = (float*)d_ws;                       // (B,N,32)
  float* fagg   = feat_t + (size_t)BB*NN*32;          // (B,N,32)

  k_pre<<<BB*NN/256 + 1, 256, 0, stream>>>(feature, feat_t,
    (const float*)d_in[2],(const float*)d_in[3],(const float*)d_in[4],(const float*)d_in[5],
    (const float*)d_in[6],(const float*)d_in[7],
    (const float*)d_in[8],(const float*)d_in[9],
    (const float*)d_in[10],(const float*)d_in[11],(const float*)d_in[12],(const float*)d_in[13],
    (const float*)d_in[14],(const float*)d_in[15],
    (const float*)d_in[16],(const float*)d_in[17],(const float*)d_in[18],(const float*)d_in[19],
    (const float*)d_in[20],(const float*)d_in[21],
    (const float*)d_in[22],(const float*)d_in[23],
    (const float*)d_in[24],(const float*)d_in[25],(const float*)d_in[26],(const float*)d_in[27],
    (const float*)d_in[28],(const float*)d_in[29]);
  k_stage1<<<BB*NN/16, 256, 0, stream>>>(xyz, feat_t, nidx, fagg);
  k_stage2<<<BB*NN/16, 256, 0, stream>>>(xyz, fagg, nidx, (float*)d_out);
}